// Round 7
// baseline (251.595 us; speedup 1.0000x reference)
//
#include <hip/hip_runtime.h>
#include <hip/hip_bf16.h>

// ---------------------------------------------------------------------------
// AttentionLayer: out = quirky_softmax(mask * (Q K^T)) @ V
//   denom[j] = sum_k exp(mask[j,k]*S[j,k])  (row sums)
//   softmax[i,j] = E[i,j] / denom[j]        (column-indexed denom!)
//   => out = E @ (V scaled per-row by 1/denom)
// R4: E + scaled-V in fp8 e4m3; out-GEMM in fp8 MFMA (verified, kept).
// R5-R10: six K-loop schedules all null at ~21% MfmaUtil -> staging-BW-bound,
//     not schedule-bound. Staging (256 MB/dispatch for qkt) served at only
//     ~5.7 TB/s because per-XCD working set (2 Q + 16 K panels = 9 MB) blows
//     the 4 MB L2 -> everything re-fetches through L3.
// R11: 2D XCD-chunked tile mapping (single variable). Grid partitioned into
//     8 rectangular regions (xcd = bid&7, idx = bid>>3 row-major in-region):
//     qkt 4mx8n (6 MB/XCD), qkv 4mx6n (5 MB), out_fp8 8mx8n (6 MB). Panel
//     repeat-reads now hit local L2 instead of L3. Everything else = R10.
// ---------------------------------------------------------------------------

#define N_TOK 4096
#define D_DIM 1024
#define VS_SCALE 131072.0f        // 2^17: lifts V/denom (~7e-6) into fp8 range

typedef __bf16 bf16x8 __attribute__((ext_vector_type(8)));
typedef __bf16 bf16x4 __attribute__((ext_vector_type(4)));
typedef float  f32x4  __attribute__((ext_vector_type(4)));

typedef const __attribute__((address_space(1))) char g_char;
typedef __attribute__((address_space(3))) char lds_char;

__device__ inline unsigned char f32_to_fp8(float f) {
    return (unsigned char)(__builtin_amdgcn_cvt_pk_fp8_f32(f, f, 0, false) & 0xff);
}

// 2D XCD-chunked bijective tile map. Grid must have gridDim.x % CN == 0,
// (gridDim.x/CN)*(gridDim.y/CM) == 8, and gridDim.x*gridDim.y == 8*CM*CN.
// XCD r (= bid&7, round-robin dispatch heuristic) owns region
// (r / nRegCols, r % nRegCols) of CM x CN tiles; idx walks it row-major.
template <int CM, int CN>
__device__ __forceinline__ void xcd_tile(int& mi, int& ni) {
    const int nbx = gridDim.x;
    const int bid = blockIdx.y * nbx + blockIdx.x;
    const int xcd = bid & 7;
    const int idx = bid >> 3;               // 0 .. CM*CN-1
    const int nRegCols = nbx / CN;
    mi = (xcd / nRegCols) * CM + idx / CN;
    ni = (xcd % nRegCols) * CN + idx % CN;
}

// ---------------------------------------------------------------------------
// fp32 -> bf16 convert (blocks 0..4095) + bias concat (blocks 4096..4107)
// ---------------------------------------------------------------------------
__global__ void cvt_and_bias(const float* __restrict__ x, __bf16* __restrict__ xb,
                             const float* __restrict__ bq, const float* __restrict__ bk,
                             const float* __restrict__ bv, float* __restrict__ bcat) {
    int b = blockIdx.x;
    if (b < 4096) {
        int i = (b * 256 + threadIdx.x) * 4;
        float4 v = *(const float4*)(x + i);
        bf16x4 o;
        o.x = (__bf16)v.x; o.y = (__bf16)v.y;
        o.z = (__bf16)v.z; o.w = (__bf16)v.w;
        *(bf16x4*)(xb + i) = o;
    } else {
        int i = (b - 4096) * 256 + threadIdx.x;
        if (i < 1024) bcat[i] = bq[i];
        else if (i < 2048) bcat[i] = bk[i - 1024];
        else if (i < 3072) bcat[i] = bv[i - 2048];
    }
}

// ---------------------------------------------------------------------------
// Transpose three 1024x1024 fp32 W -> bf16 [out][in], concatenated
// ---------------------------------------------------------------------------
__global__ void transpose_w3(const float* __restrict__ Wq, const float* __restrict__ Wk,
                             const float* __restrict__ Wv, __bf16* __restrict__ outT) {
    const float* in = (blockIdx.z == 0) ? Wq : (blockIdx.z == 1) ? Wk : Wv;
    __bf16* oT = outT + (size_t)blockIdx.z * 1024 * 1024;
    __shared__ float t[64][65];
    const int c0 = blockIdx.x * 64, r0 = blockIdx.y * 64;
    const int tid = threadIdx.x;
#pragma unroll
    for (int k = 0; k < 16; k++) {
        int lin = tid + k * 256;
        int r = lin >> 6, c = lin & 63;
        t[r][c] = in[(size_t)(r0 + r) * 1024 + c0 + c];
    }
    __syncthreads();
#pragma unroll
    for (int k = 0; k < 16; k++) {
        int lin = tid + k * 256;
        int c = lin >> 6, r = lin & 63;
        oT[(size_t)(c0 + c) * 1024 + r0 + r] = (__bf16)t[r][c];
    }
}

// ---------------------------------------------------------------------------
// VsT[d][j] = fp8( VS_SCALE * V[j][d] / denom[j] ), V row stride ldv
// ---------------------------------------------------------------------------
__global__ void scale_transpose(const __bf16* __restrict__ V, int ldv,
                                const float* __restrict__ denom,
                                unsigned char* __restrict__ VT8) {
    __shared__ float t[64][65];
    __shared__ float rd[64];
    const int d0 = blockIdx.x * 64, j0 = blockIdx.y * 64;
    const int tid = threadIdx.x;
    if (tid < 64) rd[tid] = VS_SCALE / denom[j0 + tid];
    __syncthreads();
#pragma unroll
    for (int k = 0; k < 16; k++) {
        int lin = tid + k * 256;
        int j = lin >> 6, d = lin & 63;
        t[j][d] = (float)V[(size_t)(j0 + j) * ldv + d0 + d] * rd[j];
    }
    __syncthreads();
#pragma unroll
    for (int k = 0; k < 16; k++) {
        int lin = tid + k * 256;
        int d = lin >> 6, j = lin & 63;
        VT8[(size_t)(d0 + d) * N_TOK + j0 + j] = f32_to_fp8(t[j][d]);
    }
}

// ---------------------------------------------------------------------------
// NT GEMM body (bf16): C = A * B^T, fp32 acc. 256x256 tile, 512 thr / 8
// waves (2Mx4N), per-wave 128x64. R10 counted-vmcnt + counted-lgkm ring
// (BK=32, 4x32KB slots), verified. Tile mapping = xcd_tile<CM,CN>.
// EPI 0: Cb = bf16(acc + bias[col])
// EPI 1: C8 = fp8(exp(mask*acc)); denom[row] += rowsum (atomic)
// ---------------------------------------------------------------------------
template <int EPI, int CM, int CN>
__device__ __forceinline__
void gemm_nt_body(const __bf16* __restrict__ A, const __bf16* __restrict__ B,
                  int lda, int ldb, int ldc, int K,
                  const float* __restrict__ bias,
                  const float* __restrict__ mask,
                  __bf16* __restrict__ Cb, unsigned char* __restrict__ C8,
                  float* __restrict__ denom) {
    __shared__ __bf16 ldsb[4 * 16384];   // 4 slots x 32 KB = 128 KB

    const int tid  = threadIdx.x;
    const int wave = tid >> 6;
    const int lane = tid & 63;
    const int quad = lane >> 4;
    const int l16  = lane & 15;

    int mi, ni;
    xcd_tile<CM, CN>(mi, ni);
    const int m0 = mi * 256;
    const int n0 = ni * 256;

    const int wr = (wave >> 2) * 128;   // 2 row groups
    const int wc = (wave & 3) * 64;     // 4 col groups

    // ---- staging addresses (R7-verified) ----
    const size_t lda_b = (size_t)lda * 2;
    const size_t ldb_b = (size_t)ldb * 2;
    const int trow = tid >> 2;
    const int tcs  = ((tid & 3) ^ ((tid >> 3) & 3)) * 16;
    const char* gA = (const char*)A + (size_t)(m0 + trow) * lda_b + tcs;
    const char* gB = (const char*)B + (size_t)(n0 + trow) * ldb_b + tcs;
    const size_t rstepA = 128 * lda_b;
    const size_t rstepB = 128 * ldb_b;

    lds_char* lw = (lds_char*)(void*)ldsb + tid * 16;

    // ---- read addresses (R7-verified, 0 bank conflicts) ----
    const int cswz = (quad ^ ((l16 >> 1) & 3)) * 16;
    const int aOff = (wr + l16) * 64 + cswz;            // + i*1024 per frag
    const int bOff = (wc + l16) * 64 + cswz + 16384;    // + j*1024 per frag

    f32x4 acc[8][4];
#pragma unroll
    for (int i = 0; i < 8; i++)
#pragma unroll
        for (int j = 0; j < 4; j++) acc[i][j] = (f32x4){0.f, 0.f, 0.f, 0.f};

    const int H = K >> 5;   // number of BK=32 slots (=32 at K=1024)
    const char* lbase = (const char*)(const void*)ldsb;

    bf16x8 a0[8], a1[8], bC[4];

#define STAGEH(hh) do {                                                              \
    const char* ga_ = gA + (size_t)(hh) * 64;                                        \
    const char* gb_ = gB + (size_t)(hh) * 64;                                        \
    lds_char* ls_ = lw + ((hh) & 3) * 32768;                                         \
    __builtin_amdgcn_global_load_lds((g_char*)(ga_),          ls_,          16, 0, 0); \
    __builtin_amdgcn_global_load_lds((g_char*)(ga_ + rstepA), ls_ + 8192,   16, 0, 0); \
    __builtin_amdgcn_global_load_lds((g_char*)(gb_),          ls_ + 16384,  16, 0, 0); \
    __builtin_amdgcn_global_load_lds((g_char*)(gb_ + rstepB), ls_ + 24576,  16, 0, 0); \
} while (0)

#define READ_A8(AV, slot) do {                                                       \
    const char* sb_ = lbase + (slot) * 32768;                                        \
    _Pragma("unroll")                                                                \
    for (int i_ = 0; i_ < 8; i_++)                                                   \
        AV[i_] = *(const bf16x8*)(sb_ + aOff + i_ * 1024);                           \
} while (0)

#define READ_B4(slot) do {                                                           \
    const char* sb_ = lbase + (slot) * 32768;                                        \
    _Pragma("unroll")                                                                \
    for (int j_ = 0; j_ < 4; j_++)                                                   \
        bC[j_] = *(const bf16x8*)(sb_ + bOff + j_ * 1024);                           \
} while (0)

#define MFMA32(AU) do {                                                              \
    _Pragma("unroll")                                                                \
    for (int i_ = 0; i_ < 8; i_++)                                                   \
    _Pragma("unroll")                                                                \
    for (int j_ = 0; j_ < 4; j_++)                                                   \
        acc[i_][j_] = __builtin_amdgcn_mfma_f32_16x16x32_bf16(                       \
            AU[i_], bC[j_], acc[i_][j_], 0, 0, 0);                                   \
} while (0)

    // phase h: MFMA uses A-set read last phase; reads next slot's A into AV.
#define PHASE(hh, AU, AV) do {                                                       \
    const bool pf1_ = (hh) + 1 < H;                                                  \
    const bool pf2_ = (hh) + 2 < H;                                                  \
    if (pf1_) {                                                                      \
        if (pf2_) asm volatile("s_waitcnt vmcnt(4)" ::: "memory");                   \
        else      asm volatile("s_waitcnt vmcnt(0)" ::: "memory");                   \
    }                                                                                \
    __builtin_amdgcn_s_barrier();                                                    \
    if ((hh) + 3 < H) STAGEH((hh) + 3);                                              \
    READ_B4((hh) & 3);                                                               \
    if (pf1_) READ_A8(AV, ((hh) + 1) & 3);                                           \
    if (pf1_) asm volatile("s_waitcnt lgkmcnt(8)" ::: "memory");                     \
    else      asm volatile("s_waitcnt lgkmcnt(0)" ::: "memory");                     \
    __builtin_amdgcn_sched_barrier(0);                                               \
    __builtin_amdgcn_s_setprio(1);                                                   \
    MFMA32(AU);                                                                      \
    __builtin_amdgcn_s_setprio(0);                                                   \
    __builtin_amdgcn_sched_barrier(0);                                               \
} while (0)

    // prologue: stage slots 0,1,2 (12 loads); force slot0; publish; read A(0)
    STAGEH(0);
    STAGEH(1);
    STAGEH(2);
    asm volatile("s_waitcnt vmcnt(8)" ::: "memory");
    __builtin_amdgcn_s_barrier();
    READ_A8(a0, 0);

    for (int h0 = 0; h0 < H; h0 += 2) {
        PHASE(h0,     a0, a1);
        PHASE(h0 + 1, a1, a0);
    }
#undef STAGEH
#undef READ_A8
#undef READ_B4
#undef MFMA32
#undef PHASE

    // ---- epilogue: C/D layout col=lane&15, row=quad*4+reg ----
    if (EPI == 0) {
#pragma unroll
        for (int i = 0; i < 8; i++) {
            const int rbase = m0 + wr + i * 16 + quad * 4;
#pragma unroll
            for (int j = 0; j < 4; j++) {
                const int col = n0 + wc + j * 16 + l16;
                f32x4 v = acc[i][j];
                const float bb = bias[col];
#pragma unroll
                for (int r = 0; r < 4; r++)
                    Cb[(size_t)(rbase + r) * ldc + col] = (__bf16)(v[r] + bb);
            }
        }
    } else {
        // 2-deep chunk-pipelined mask prefetch (R9).
        const float* mrow = mask + (size_t)(m0 + wr + quad * 4) * (size_t)ldc
                            + (n0 + wc + l16);
        unsigned char* crow = C8 + (size_t)(m0 + wr + quad * 4) * (size_t)ldc
                            + (n0 + wc + l16);
        float mk0[4][4], mk1[4][4];
#define LOADC(dst, ii) do {                                                         \
    _Pragma("unroll")                                                               \
    for (int j = 0; j < 4; j++)                                                     \
    _Pragma("unroll")                                                               \
    for (int r = 0; r < 4; r++)                                                     \
        dst[j][r] = mrow[(size_t)((ii) * 16 + r) * (size_t)ldc + j * 16];           \
} while (0)
#define CONSUME(ii, mk) do {                                                        \
    f32x4 rs = (f32x4){0.f, 0.f, 0.f, 0.f};                                         \
    _Pragma("unroll")                                                               \
    for (int j = 0; j < 4; j++) {                                                   \
        f32x4 v = acc[ii][j];                                                       \
        _Pragma("unroll")                                                           \
        for (int r = 0; r < 4; r++) {                                               \
            float e = __expf(mk[j][r] * v[r]);                                      \
            crow[(size_t)((ii) * 16 + r) * (size_t)ldc + j * 16] = f32_to_fp8(e);   \
            rs[r] += e;                                                             \
        }                                                                           \
    }                                                                               \
    _Pragma("unroll")                                                               \
    for (int m = 1; m < 16; m <<= 1)                                                \
        _Pragma("unroll")                                                           \
        for (int r = 0; r < 4; r++) rs[r] += __shfl_xor(rs[r], m, 64);              \
    if (l16 == 0) {                                                                 \
        const int rb = m0 + wr + (ii) * 16 + quad * 4;                              \
        _Pragma("unroll")                                                           \
        for (int r = 0; r < 4; r++) atomicAdd(&denom[rb + r], rs[r]);               \
    }                                                                               \
} while (0)
        LOADC(mk0, 0);
        LOADC(mk1, 1);
        CONSUME(0, mk0); __builtin_amdgcn_sched_barrier(0);
        LOADC(mk0, 2);
        CONSUME(1, mk1); __builtin_amdgcn_sched_barrier(0);
        LOADC(mk1, 3);
        CONSUME(2, mk0); __builtin_amdgcn_sched_barrier(0);
        LOADC(mk0, 4);
        CONSUME(3, mk1); __builtin_amdgcn_sched_barrier(0);
        LOADC(mk1, 5);
        CONSUME(4, mk0); __builtin_amdgcn_sched_barrier(0);
        LOADC(mk0, 6);
        CONSUME(5, mk1); __builtin_amdgcn_sched_barrier(0);
        LOADC(mk1, 7);
        CONSUME(6, mk0); __builtin_amdgcn_sched_barrier(0);
        CONSUME(7, mk1);
#undef LOADC
#undef CONSUME
    }
}

// ---- named wrappers (distinct rocprof rows) ----
// qkt grid 16x16: regions 4m x 8n -> per-XCD 4 Q + 8 K panels ~= 6 MB.
// qkv grid 16x12: regions 4m x 6n -> ~5 MB.
__global__ __launch_bounds__(512, 1)
void gemm_qkv(const __bf16* __restrict__ A, const __bf16* __restrict__ B,
              int lda, int ldb, int ldc, int K,
              const float* __restrict__ bias,
              __bf16* __restrict__ Cb) {
    gemm_nt_body<0, 4, 6>(A, B, lda, ldb, ldc, K, bias, nullptr, Cb, nullptr, nullptr);
}

__global__ __launch_bounds__(512, 1)
void gemm_qkt(const __bf16* __restrict__ A, const __bf16* __restrict__ B,
              int lda, int ldb, int ldc, int K,
              const float* __restrict__ mask,
              unsigned char* __restrict__ C8, float* __restrict__ denom) {
    gemm_nt_body<1, 4, 8>(A, B, lda, ldb, ldc, K, nullptr, mask, nullptr, C8, denom);
}

// ---------------------------------------------------------------------------
// out GEMM (fp8): C[4096][1024] = E[4096][4096] * VsT[1024][4096]^T, BK=128.
// 128x64 tile, 4 waves each 64x32 (4x2 frags). R0-verified loop; tile map
// now xcd_tile<8,8> (grid 32m x 16n -> 8 regions of 8x8, ~6 MB/XCD).
// ---------------------------------------------------------------------------
__global__ __launch_bounds__(256, 2)
void gemm_out_fp8(const unsigned char* __restrict__ A,
                  const unsigned char* __restrict__ B,
                  float* __restrict__ C) {
    __shared__ unsigned char lA[128 * 128];
    __shared__ unsigned char lB[64 * 128];

    const int tid  = threadIdx.x;
    const int wave = tid >> 6;
    const int lane = tid & 63;
    const int quad = lane >> 4;
    const int l16  = lane & 15;

    int mi, ni;
    xcd_tile<8, 8>(mi, ni);
    const int m0 = mi * 128;
    const int n0 = ni * 64;

    const int wr = (wave >> 1) * 64;
    const int wc = (wave & 1) * 32;

    const int tr = tid >> 3;
    const int ts = ((tid & 7) ^ (tr & 7)) * 16;
    const char* gA = (const char*)A + (size_t)(m0 + tr) * N_TOK + ts;
    const char* gB = (const char*)B + (size_t)(n0 + tr) * N_TOK + ts;
    const size_t pstep = (size_t)32 * N_TOK;

    lds_char* lAp = (lds_char*)(void*)lA + wave * 1024;
    lds_char* lBp = (lds_char*)(void*)lB + wave * 1024;

    // read addr: row*128 + ((kstep*2 + (quad>>1)) ^ (l16&7))*16 + (quad&1)*8
    const int l7 = l16 & 7;
    const int qhi = quad >> 1, qlo = (quad & 1) * 8;
    int rdA[4], rdB[4];
#pragma unroll
    for (int k = 0; k < 4; k++) {
        rdA[k] = ((k * 2 + qhi) ^ l7) * 16 + qlo;   // add row*128 per-frag
        rdB[k] = rdA[k];
    }

    f32x4 acc[4][2];
#pragma unroll
    for (int i = 0; i < 4; i++)
#pragma unroll
        for (int j = 0; j < 2; j++) acc[i][j] = (f32x4){0.f, 0.f, 0.f, 0.f};

    for (int kt = 0; kt < N_TOK; kt += 128) {
#pragma unroll
        for (int c = 0; c < 4; c++)
            __builtin_amdgcn_global_load_lds((g_char*)(gA + c * pstep),
                                             lAp + c * 4096, 16, 0, 0);
#pragma unroll
        for (int c = 0; c < 2; c++)
            __builtin_amdgcn_global_load_lds((g_char*)(gB + c * pstep),
                                             lBp + c * 4096, 16, 0, 0);
        gA += 128;
        gB += 128;
        __syncthreads();

#pragma unroll
        for (int k = 0; k < 4; k++) {
            long a[4], b[2];
#pragma unroll
            for (int i = 0; i < 4; i++)
                a[i] = *(const long*)&lA[(wr + i * 16 + l16) * 128 + rdA[k]];
#pragma unroll
            for (int j = 0; j < 2; j++)
                b[j] = *(const long*)&lB[(wc + j * 16 + l16) * 128 + rdB[k]];
#pragma unroll
            for (int i = 0; i < 4; i++)
#pragma unroll
                for (int j = 0; j < 2; j++)
                    acc[i][j] = __builtin_amdgcn_mfma_f32_16x16x32_fp8_fp8(
                        a[i], b[j], acc[i][j], 0, 0, 0);
        }
        __syncthreads();
    }

#pragma unroll
    for (int i = 0; i < 4; i++) {
#pragma unroll
        for (int j = 0; j < 2; j++) {
            const int col   = n0 + wc + j * 16 + l16;
            const int rbase = m0 + wr + i * 16 + quad * 4;
            f32x4 v = acc[i][j];
#pragma unroll
            for (int r = 0; r < 4; r++)
                C[(size_t)(rbase + r) * D_DIM + col] = v[r] * (1.0f / VS_SCALE);
        }
    }
}

// ---------------------------------------------------------------------------
extern "C" void kernel_launch(void* const* d_in, const int* in_sizes, int n_in,
                              void* d_out, int out_size, void* d_ws, size_t ws_size,
                              hipStream_t stream) {
    const float* x    = (const float*)d_in[0];
    const float* mask = (const float*)d_in[1];
    const float* Wq   = (const float*)d_in[2];
    const float* bq   = (const float*)d_in[3];
    const float* Wk   = (const float*)d_in[4];
    const float* bk   = (const float*)d_in[5];
    const float* Wv   = (const float*)d_in[6];
    const float* bv   = (const float*)d_in[7];
    float* out = (float*)d_out;
    char* ws = (char*)d_ws;

    const size_t MB = 1024 * 1024;
    unsigned char* E8   = (unsigned char*)(ws + 0 * MB);   // 16 MB [4096][4096] fp8
    __bf16* QKVb  = (__bf16*)(ws + 16 * MB);               // 24 MB [4096][3072]
    __bf16* xb    = (__bf16*)(ws + 40 * MB);               // 8 MB [4096][1024]
    unsigned char* VsT8 = (unsigned char*)xb;              // 4 MB (reuses dead xb)
    __bf16* WcatT = (__bf16*)(ws + 48 * MB);               // 6 MB [3072][1024]
    float*  bcat  = (float*)(ws + 54 * MB);                // 12 KB
    float*  denom = (float*)(ws + 54 * MB + 64 * 1024);    // 16 KB

    hipMemsetAsync(denom, 0, N_TOK * sizeof(float), stream);

    // ---- prep ----
    cvt_and_bias<<<4096 + 12, 256, 0, stream>>>(x, xb, bq, bk, bv, bcat);
    transpose_w3<<<dim3(16, 16, 3), 256, 0, stream>>>(Wq, Wk, Wv, WcatT);

    // ---- fused QKV projection: [4096][3072] = xb @ WcatT^T ----
    gemm_qkv<<<dim3(12, 16), 512, 0, stream>>>(
        xb, WcatT, D_DIM, D_DIM, 3 * D_DIM, D_DIM, bcat, QKVb);

    // ---- E = exp(mask * (Q K^T)) -> fp8; denom[row] += rowsum ----
    const __bf16* Qb = QKVb;
    const __bf16* Kb = QKVb + D_DIM;
    gemm_qkt<<<dim3(16, 16), 512, 0, stream>>>(
        Qb, Kb, 3 * D_DIM, 3 * D_DIM, N_TOK, D_DIM, mask, E8, denom);

    // ---- VsT8[d][j] = fp8(VS_SCALE * V[j][d] / denom[j]) ----
    scale_transpose<<<dim3(16, 64), 256, 0, stream>>>(QKVb + 2048, 3 * D_DIM, denom, VsT8);

    // ---- out = (E8 @ VsT8^T) / VS_SCALE ----
    gemm_out_fp8<<<dim3(16, 32), 256, 0, stream>>>(E8, VsT8, out);
}